// Round 6
// baseline (595.524 us; speedup 1.0000x reference)
//
#include <hip/hip_runtime.h>
#include <stdint.h>

// Problem constants (fixed by reference)
#define M_DIM 8192   // 4 * 2048
#define N_DIM 4096   // OUT_F
#define K_DIM 4096   // IN_F
#define GPR   16     // groups per output row = K/256

typedef _Float16 half8 __attribute__((ext_vector_type(8)));  // 8 fp16 = 4 VGPR (MFMA A/B frag)
typedef float f32x4 __attribute__((ext_vector_type(4)));     // MFMA C/D frag

union h16cvt { _Float16 h; unsigned short u; };

__device__ __forceinline__ unsigned short f32_to_f16_bits(float f) {
  h16cvt c; c.h = (_Float16)f;  // v_cvt_f16_f32, RNE; exact for ints |n|<=2048
  return c.u;
}
__device__ __forceinline__ uint32_t pack2_f16(float a, float b) {
  return (uint32_t)f32_to_f16_bits(a) | ((uint32_t)f32_to_f16_bits(b) << 16);
}

// ---------- merged precompute, grid-stride (G11: ~2048 blocks, 32 waves/CU) ----------
// W part (blocks [0,512)): Wq = (q - z) exact fp16. X part (blocks [512,2048)): x -> fp16.
#define PRE_WBLK 512
#define PRE_XBLK 1536
__global__ void precompute_kernel(const int* __restrict__ q,
                                  const float* __restrict__ zeros,
                                  const float* __restrict__ x,
                                  unsigned short* __restrict__ wq,
                                  unsigned short* __restrict__ xh) {
  if (blockIdx.x < PRE_WBLK) {
    const int stride = PRE_WBLK * 256;
    const int total = N_DIM * K_DIM / 4;                  // 4.19M 16B-chunks, 32 iters/thread
    for (int idx = blockIdx.x * 256 + threadIdx.x; idx < total; idx += stride) {
      const int4 qa = reinterpret_cast<const int4*>(q)[idx];
      const float z = zeros[(idx * 4) >> 8];              // 4-chunk never crosses a 256-group
      uint2 o;
      o.x = pack2_f16((float)qa.x - z, (float)qa.y - z);
      o.y = pack2_f16((float)qa.z - z, (float)qa.w - z);
      reinterpret_cast<uint2*>(wq)[idx] = o;
    }
  } else {
    const int stride = PRE_XBLK * 256;
    const int total = M_DIM * K_DIM / 4;                  // 8.39M chunks, ~22 iters/thread
    for (int idx = (blockIdx.x - PRE_WBLK) * 256 + threadIdx.x; idx < total; idx += stride) {
      const float4 v = reinterpret_cast<const float4*>(x)[idx];
      uint2 o;
      o.x = pack2_f16(v.x, v.y);
      o.y = pack2_f16(v.z, v.w);
      reinterpret_cast<uint2*>(xh)[idx] = o;
    }
  }
}

// ---------- async global->LDS, 16B/lane ----------
__device__ __forceinline__ void load_lds16(const unsigned short* g, unsigned short* l) {
  __builtin_amdgcn_global_load_lds(
      (const __attribute__((address_space(1))) uint32_t*)g,
      (__attribute__((address_space(3))) uint32_t*)l, 16, 0, 0);
}

// ================= 256x256 pipelined GEMM, 8 waves, counted vmcnt =================
// BM=BN=256, BK=64, 512 thr (2Mx4N waves). Per-wave C: 128x64 = 8x4 16x16 frags.
// LDS: A/B double-buffered [2][256*64] fp16 = 128 KiB. 1 block/CU, grid 512 (=2 rounds).
// Pipeline per K-tile kt (c = kt&1):
//   [rescale if group boundary]
//   s_barrier                 -- all waves done READING buf c^1 (prev iter)
//   stage tile kt+1 -> buf c^1  (8 global_load_lds/wave; dummy re-stage at kt=63)
//   s_waitcnt vmcnt(8)        -- own tile-kt loads landed (kt+1's 8 stay IN FLIGHT)
//   s_barrier                 -- everyone's tile-kt loads landed
//   4 MFMA phases on buf c (gray-code quadrants, setprio, sched_barrier-pinned)
// Loads for tile kt are issued a full tile (~2500 cyc) before consumption and are
// never drained to 0 inside the loop (T4). T2 swizzle identical to verified 128² kernel.
#define BM2 256
#define BN2 256
#define BK2 64

__device__ __forceinline__ void stage_tile512(const unsigned short* __restrict__ src,
                                              unsigned short* lds,
                                              int row0, int k0, int t, int lane, int wave) {
#pragma unroll
  for (int i = 0; i < 4; ++i) {
    const int base = i * 512 + wave * 64;   // wave-uniform 16B-block index
    const int idx = base + lane;            // this lane's 16B block (== i*512 + t)
    const int row = idx >> 3;               // 8 blocks (64 fp16) per row
    const int kbs = (idx & 7) ^ (row & 7);  // inverse-swizzled source block (T2)
    load_lds16(src + (size_t)(row0 + row) * K_DIM + k0 + kbs * 8,
               lds + (size_t)base * 8);     // wave-uniform LDS base, linear dest
  }
}

__global__ __launch_bounds__(512, 2)
void qgemm256_kernel(const unsigned short* __restrict__ X16,
                     const unsigned short* __restrict__ Wq,
                     const float* __restrict__ scales,
                     const float* __restrict__ bias,
                     float* __restrict__ out) {
  __shared__ __attribute__((aligned(16))) unsigned short sA[2][BM2 * BK2];
  __shared__ __attribute__((aligned(16))) unsigned short sB[2][BN2 * BK2];

  const int t = threadIdx.x;
  const int lane = t & 63;
  const int wave = t >> 6;
  const int wm = wave >> 2;   // 0..1 : wave row   (owns C rows wm*128 + [0,128))
  const int wn = wave & 3;    // 0..3 : wave col   (owns C cols wn*64  + [0,64))
  const int cl = lane & 15;   // frag row (A) / frag col (B, C/D)
  const int kh = lane >> 4;   // lane-group 0..3

  // XCD-aware bijective swizzle (nwg=512, %8==0)
  const int nwg = gridDim.x;
  const int bid = blockIdx.x;
  const int wg = (bid & 7) * (nwg >> 3) + (bid >> 3);
  const int tm = wg >> 4;     // M/BM2 = 32 rows of tiles
  const int tn = wg & 15;     // N/BN2 = 16 cols of tiles
  const int m0 = tm * BM2, n0 = tn * BN2;

  f32x4 acc[8][4];
#pragma unroll
  for (int i = 0; i < 8; ++i)
#pragma unroll
    for (int j = 0; j < 4; ++j)
#pragma unroll
      for (int r = 0; r < 4; ++r) acc[i][j][r] = 0.0f;

  // Flash-style group rescale state: acc kept in units of 1/s_g.
  const int scol = n0 + wn * 64 + cl;  // + nf*16
  float s_cur[4];
#pragma unroll
  for (int nf = 0; nf < 4; ++nf)
    s_cur[nf] = scales[(size_t)(scol + nf * 16) * GPR];

  // Prologue: tile 0 -> buf 0
  stage_tile512(X16, sA[0], m0, 0, t, lane, wave);
  stage_tile512(Wq,  sB[0], n0, 0, t, lane, wave);

  for (int kt = 0; kt < 64; ++kt) {
    const int c = kt & 1;
    unsigned short* lA = sA[c];
    unsigned short* lB = sB[c];

    // Group-boundary rescale (register-only, uniform branch)
    if ((kt > 0) && ((kt & 3) == 0)) {
      const int g = kt >> 2;
#pragma unroll
      for (int nf = 0; nf < 4; ++nf) {
        const float s_new = scales[(size_t)(scol + nf * 16) * GPR + g];
        const float r = s_cur[nf] / s_new;
        s_cur[nf] = s_new;
#pragma unroll
        for (int mf = 0; mf < 8; ++mf)
#pragma unroll
          for (int q2 = 0; q2 < 4; ++q2) acc[mf][nf][q2] *= r;
      }
    }

    __builtin_amdgcn_s_barrier();   // all waves done reading buf c^1 (prev iteration)

    {  // Prefetch tile kt+1 into buf c^1 (kt=63: harmless dummy re-stage of tile 0,
       // keeps vmcnt arithmetic uniform; that buffer is not read again)
      const int nk = (kt + 1) & 63;
      const int k1 = nk * BK2;
      stage_tile512(X16, sA[c ^ 1], m0, k1, t, lane, wave);
      stage_tile512(Wq,  sB[c ^ 1], n0, k1, t, lane, wave);
    }

    // Counted wait: own outstanding = 8 (tile kt, issued last iter) + 8 (just issued).
    // vmcnt(8) retires tile kt's loads; tile kt+1's stay in flight across the MFMAs.
    asm volatile("s_waitcnt vmcnt(8)" ::: "memory");
    __builtin_amdgcn_s_barrier();   // ALL waves' tile-kt loads landed

    // ---- 4 MFMA phases, gray-code quadrant order for frag reuse ----
    // frag addr: row&7 == cl&7 for A and B; stored k-block = logical ^ (cl&7)
    half8 av[4][2], bv0[2][2], bv1[2][2];
#define LDA(row_, ks_) (*reinterpret_cast<const half8*>(&lA[(row_) * BK2 + ((((ks_)*4 + kh) ^ (cl & 7)) * 8)]))
#define LDB(row_, ks_) (*reinterpret_cast<const half8*>(&lB[(row_) * BK2 + ((((ks_)*4 + kh) ^ (cl & 7)) * 8)]))

    // P1: (mh0, nh0) -- load A mf0-3, B nf0-1
#pragma unroll
    for (int m = 0; m < 4; ++m)
#pragma unroll
      for (int ks = 0; ks < 2; ++ks) av[m][ks] = LDA(wm * 128 + m * 16 + cl, ks);
#pragma unroll
    for (int n = 0; n < 2; ++n)
#pragma unroll
      for (int ks = 0; ks < 2; ++ks) bv0[n][ks] = LDB(wn * 64 + n * 16 + cl, ks);
    __builtin_amdgcn_s_setprio(1);
#pragma unroll
    for (int m = 0; m < 4; ++m)
#pragma unroll
      for (int n = 0; n < 2; ++n)
#pragma unroll
        for (int ks = 0; ks < 2; ++ks)
          acc[m][n] = __builtin_amdgcn_mfma_f32_16x16x32_f16(av[m][ks], bv0[n][ks], acc[m][n], 0, 0, 0);
    __builtin_amdgcn_s_setprio(0);
    __builtin_amdgcn_sched_barrier(0);

    // P2: (mh0, nh1) -- load B nf2-3, reuse A mf0-3
#pragma unroll
    for (int n = 0; n < 2; ++n)
#pragma unroll
      for (int ks = 0; ks < 2; ++ks) bv1[n][ks] = LDB(wn * 64 + (n + 2) * 16 + cl, ks);
    __builtin_amdgcn_s_setprio(1);
#pragma unroll
    for (int m = 0; m < 4; ++m)
#pragma unroll
      for (int n = 0; n < 2; ++n)
#pragma unroll
        for (int ks = 0; ks < 2; ++ks)
          acc[m][n + 2] = __builtin_amdgcn_mfma_f32_16x16x32_f16(av[m][ks], bv1[n][ks], acc[m][n + 2], 0, 0, 0);
    __builtin_amdgcn_s_setprio(0);
    __builtin_amdgcn_sched_barrier(0);

    // P3: (mh1, nh1) -- load A mf4-7, reuse B nf2-3
#pragma unroll
    for (int m = 0; m < 4; ++m)
#pragma unroll
      for (int ks = 0; ks < 2; ++ks) av[m][ks] = LDA(wm * 128 + (m + 4) * 16 + cl, ks);
    __builtin_amdgcn_s_setprio(1);
#pragma unroll
    for (int m = 0; m < 4; ++m)
#pragma unroll
      for (int n = 0; n < 2; ++n)
#pragma unroll
        for (int ks = 0; ks < 2; ++ks)
          acc[m + 4][n + 2] = __builtin_amdgcn_mfma_f32_16x16x32_f16(av[m][ks], bv1[n][ks], acc[m + 4][n + 2], 0, 0, 0);
    __builtin_amdgcn_s_setprio(0);
    __builtin_amdgcn_sched_barrier(0);

    // P4: (mh1, nh0) -- reuse A mf4-7 and B nf0-1 (bv0 kept live since P1)
    __builtin_amdgcn_s_setprio(1);
#pragma unroll
    for (int m = 0; m < 4; ++m)
#pragma unroll
      for (int n = 0; n < 2; ++n)
#pragma unroll
        for (int ks = 0; ks < 2; ++ks)
          acc[m + 4][n] = __builtin_amdgcn_mfma_f32_16x16x32_f16(av[m][ks], bv0[n][ks], acc[m + 4][n], 0, 0, 0);
    __builtin_amdgcn_s_setprio(0);
    __builtin_amdgcn_sched_barrier(0);
#undef LDA
#undef LDB
  }

  // Drain the dummy prefetch's LDS writes before kernel teardown / epilogue stores.
  asm volatile("s_waitcnt vmcnt(0)" ::: "memory");

  // Epilogue: C = acc * s_last + bias.  C/D: col=lane&15, row=(lane>>4)*4+reg (m89).
#pragma unroll
  for (int nf = 0; nf < 4; ++nf) {
    const int col = scol + nf * 16;
    const float bv = bias[col];
    const float sl = s_cur[nf];
#pragma unroll
    for (int mf = 0; mf < 8; ++mf) {
      const int row = m0 + wm * 128 + mf * 16 + kh * 4;
#pragma unroll
      for (int r = 0; r < 4; ++r)
        out[(size_t)(row + r) * N_DIM + col] = acc[mf][nf][r] * sl + bv;
    }
  }
}

// ---------- fallback GEMM: zero workspace, fused dequant (insurance; 128² m97) ----------
#define BM 128
#define BN 128
#define BK 64
__global__ __launch_bounds__(256, 2)
void qgemm_fused_kernel(const float* __restrict__ x,
                        const int* __restrict__ qw,
                        const float* __restrict__ scales,
                        const float* __restrict__ zeros,
                        const float* __restrict__ bias,
                        float* __restrict__ out) {
  __shared__ __attribute__((aligned(16))) unsigned short sA[BM * BK];
  __shared__ __attribute__((aligned(16))) unsigned short sB[BN * BK];

  const int t = threadIdx.x;
  const int lane = t & 63;
  const int wave = t >> 6;
  const int wm = wave >> 1;
  const int wn = wave & 1;
  const int cl = lane & 15;
  const int kh = lane >> 4;

  const int nwg = gridDim.x;
  const int bid = blockIdx.x;
  const int wg = (bid & 7) * (nwg >> 3) + (bid >> 3);
  const int tm = wg >> 5;
  const int tn = wg & 31;
  const int m0 = tm * BM, n0 = tn * BN;

  f32x4 acc[4][4];
#pragma unroll
  for (int i = 0; i < 4; ++i)
#pragma unroll
    for (int j = 0; j < 4; ++j)
#pragma unroll
      for (int r = 0; r < 4; ++r) acc[i][j][r] = 0.0f;

  const int scol = n0 + wn * 64 + cl;
  float s_cur[4];
#pragma unroll
  for (int nf = 0; nf < 4; ++nf)
    s_cur[nf] = scales[(size_t)(scol + nf * 16) * GPR];

  for (int kt = 0; kt < K_DIM / BK; ++kt) {
    const int k0 = kt * BK;
    uint4 ra[4], rb[4];
#pragma unroll
    for (int i = 0; i < 4; ++i) {
      const int idx = i * 256 + t;
      const int row = idx >> 3;
      const int kbs = (idx & 7) ^ (row & 7);
      const float4 a0 = *reinterpret_cast<const float4*>(x + (size_t)(m0 + row) * K_DIM + k0 + kbs * 8);
      const float4 a1 = *reinterpret_cast<const float4*>(x + (size_t)(m0 + row) * K_DIM + k0 + kbs * 8 + 4);
      ra[i].x = pack2_f16(a0.x, a0.y); ra[i].y = pack2_f16(a0.z, a0.w);
      ra[i].z = pack2_f16(a1.x, a1.y); ra[i].w = pack2_f16(a1.z, a1.w);
      const int gk = k0 + kbs * 8;
      const float z = zeros[(size_t)(n0 + row) * GPR + (gk >> 8)];
      const int4 q0 = *reinterpret_cast<const int4*>(qw + (size_t)(n0 + row) * K_DIM + gk);
      const int4 q1 = *reinterpret_cast<const int4*>(qw + (size_t)(n0 + row) * K_DIM + gk + 4);
      rb[i].x = pack2_f16((float)q0.x - z, (float)q0.y - z);
      rb[i].y = pack2_f16((float)q0.z - z, (float)q0.w - z);
      rb[i].z = pack2_f16((float)q1.x - z, (float)q1.y - z);
      rb[i].w = pack2_f16((float)q1.z - z, (float)q1.w - z);
    }

    if ((kt > 0) && ((kt & 3) == 0)) {
      const int g = kt >> 2;
#pragma unroll
      for (int nf = 0; nf < 4; ++nf) {
        const float s_new = scales[(size_t)(scol + nf * 16) * GPR + g];
        const float r = s_cur[nf] / s_new;
        s_cur[nf] = s_new;
#pragma unroll
        for (int mf = 0; mf < 4; ++mf)
#pragma unroll
          for (int q2 = 0; q2 < 4; ++q2) acc[mf][nf][q2] *= r;
      }
    }

    __syncthreads();
#pragma unroll
    for (int i = 0; i < 4; ++i) {
      const int idx = i * 256 + t;
      *reinterpret_cast<uint4*>(&sA[idx * 8]) = ra[i];
      *reinterpret_cast<uint4*>(&sB[idx * 8]) = rb[i];
    }
    __syncthreads();

#pragma unroll
    for (int kk = 0; kk < 2; ++kk) {
      const int blk = (kk * 4 + kh) ^ (cl & 7);
      half8 av[4], bv[4];
#pragma unroll
      for (int mf = 0; mf < 4; ++mf) {
        const int row = wm * 64 + mf * 16 + cl;
        av[mf] = *reinterpret_cast<const half8*>(&sA[row * BK + blk * 8]);
      }
#pragma unroll
      for (int nf = 0; nf < 4; ++nf) {
        const int row = wn * 64 + nf * 16 + cl;
        bv[nf] = *reinterpret_cast<const half8*>(&sB[row * BK + blk * 8]);
      }
#pragma unroll
      for (int mf = 0; mf < 4; ++mf)
#pragma unroll
        for (int nf = 0; nf < 4; ++nf)
          acc[mf][nf] = __builtin_amdgcn_mfma_f32_16x16x32_f16(av[mf], bv[nf], acc[mf][nf], 0, 0, 0);
    }
  }

#pragma unroll
  for (int nf = 0; nf < 4; ++nf) {
    const int col = scol + nf * 16;
    const float bv = bias[col];
    const float sl = s_cur[nf];
#pragma unroll
    for (int mf = 0; mf < 4; ++mf) {
      const int row = m0 + wm * 64 + mf * 16 + kh * 4;
#pragma unroll
      for (int r = 0; r < 4; ++r)
        out[(size_t)(row + r) * N_DIM + col] = acc[mf][nf][r] * sl + bv;
    }
  }
}

extern "C" void kernel_launch(void* const* d_in, const int* in_sizes, int n_in,
                              void* d_out, int out_size, void* d_ws, size_t ws_size,
                              hipStream_t stream) {
  const float* x      = (const float*)d_in[0];
  const int*   qw     = (const int*)d_in[1];
  const float* scales = (const float*)d_in[2];
  const float* zeros  = (const float*)d_in[3];
  const float* bias   = (const float*)d_in[4];
  float* out = (float*)d_out;

  const size_t MiB = 1024 * 1024;

  if (ws_size >= 96 * MiB) {
    // Fast path: precompute fp16 copies (Wq 32 MiB | X16 64 MiB), then 256² pipelined GEMM.
    unsigned short* Wq  = (unsigned short*)d_ws;
    unsigned short* X16 = (unsigned short*)((char*)d_ws + 32 * MiB);
    precompute_kernel<<<PRE_WBLK + PRE_XBLK, 256, 0, stream>>>(qw, zeros, x, Wq, X16);
    const int ngrid = (M_DIM / BM2) * (N_DIM / BN2);  // 512, %8==0 for XCD swizzle
    qgemm256_kernel<<<ngrid, 512, 0, stream>>>(X16, Wq, scales, bias, out);
  } else {
    // Insurance path: zero-workspace fused dequant GEMM (slower, always correct).
    const int ngrid = (M_DIM / BM) * (N_DIM / BN);    // 2048
    qgemm_fused_kernel<<<ngrid, 256, 0, stream>>>(x, qw, scales, zeros, bias, out);
  }
}